// Round 1
// baseline (980.749 us; speedup 1.0000x reference)
//
#include <hip/hip_runtime.h>
#include <stdint.h>

typedef short bf16x8 __attribute__((ext_vector_type(8)));
typedef float f32x4 __attribute__((ext_vector_type(4)));

#define DI __device__ __forceinline__

DI unsigned short f2bf(float f) {
    union { float f; unsigned u; } v; v.f = f;
    return (unsigned short)((v.u + 0x7fffu + ((v.u >> 16) & 1u)) >> 16);
}

DI f32x4 mfma16(bf16x8 a, bf16x8 b, f32x4 c) {
    return __builtin_amdgcn_mfma_f32_16x16x32_bf16(a, b, c, 0, 0, 0);
}

DI void gload16(const unsigned short* g, unsigned short* l) {
    __builtin_amdgcn_global_load_lds(
        (const __attribute__((address_space(1))) unsigned int*)g,
        (__attribute__((address_space(3))) unsigned int*)l, 16, 0, 0);
}

// ---------------------------------------------------------------------------
// Preprocess: convert f32 weights -> bf16 MFMA-fragment-ordered tiles in ws.
// Tile = 16 output cols x 256 k, stored as [s(0..7)][lane(0..63)][i(0..7)] bf16
// where element = W[k = 32s + 8*(lane>>4) + i][col = src_n*16 + (lane&15)].
// Global tile index g = layer*192 + tl:
//   tl   0..47  : qkv  head-major (h=tl/6, sec=(tl%6)>>1, nn=(tl%6)&1,
//                 src_n = sec*16 + 2h + nn), ldN=768
//   tl  48..63  : proj (src_n = tl-48), ldN=256
//   tl  64..127 : fc1  (src_n = tl-64), ldN=1024
//   tl 128..191 : fc2  (u=tl-128, c=u>>4, src_n=u&15, K0=c*256), ldN=256
// ---------------------------------------------------------------------------
__global__ __launch_bounds__(256)
void prep_kernel(const float* __restrict__ qkv_w, const float* __restrict__ proj_w,
                 const float* __restrict__ fc1_w, const float* __restrict__ fc2_w,
                 unsigned short* __restrict__ out)
{
    __shared__ float tile[256][17];
    const int tid = threadIdx.x;          // 256 threads
    const int tgl = blockIdx.x;           // 0..767
    const int layer = tgl / 192;
    const int tl = tgl % 192;
    const float* W; int ldN, src_n, K0 = 0;
    if (tl < 48) {
        int h = tl / 6, r6 = tl % 6, sec = r6 >> 1, nn = r6 & 1;
        W = qkv_w + (size_t)layer * 256 * 768; ldN = 768; src_n = sec * 16 + 2 * h + nn;
    } else if (tl < 64) {
        W = proj_w + (size_t)layer * 256 * 256; ldN = 256; src_n = tl - 48;
    } else if (tl < 128) {
        W = fc1_w + (size_t)layer * 256 * 1024; ldN = 1024; src_n = tl - 64;
    } else {
        int u = tl - 128;
        W = fc2_w + (size_t)layer * 1024 * 256; ldN = 256; src_n = u & 15; K0 = (u >> 4) * 256;
    }
    const int cn = tid & 15, k0 = tid >> 4;
    const float* src = W + (size_t)K0 * ldN + src_n * 16 + cn;
    #pragma unroll
    for (int p = 0; p < 16; ++p) {
        int kk = p * 16 + k0;
        tile[kk][cn] = src[(size_t)kk * ldN];
    }
    __syncthreads();
    unsigned short* dst = out + (size_t)tgl * 4096;
    #pragma unroll
    for (int blk = 0; blk < 2; ++blk) {
        int e0 = tid * 16 + blk * 8;
        int s = e0 >> 9;
        int lane = (e0 >> 3) & 63;
        int kb = s * 32 + (lane >> 4) * 8;
        int n = lane & 15;
        union { unsigned short u[8]; bf16x8 v; } pk;
        #pragma unroll
        for (int i = 0; i < 8; ++i) pk.u[i] = f2bf(tile[kb + i][n]);
        *(bf16x8*)(dst + e0) = pk.v;
    }
}

// ---------------------------------------------------------------------------
// Fused kernel: 512 blocks x 512 threads (8 waves). Wave w owns group
// G = blockIdx.x*8 + w  (b = G>>7, t = G&127): 16 tokens x 256 dims.
// Residual x in fp32 registers, C-fragment layout:
//   xr[n][r] = x[row = 4*(lane>>4)+r][col = 16n + (lane&15)]
// Weights streamed: 2 tiles (16KB) per round, double-buffered LDS.
// ---------------------------------------------------------------------------
__global__ __launch_bounds__(512, 2)
void fused_kernel(const float* __restrict__ obs, const int* __restrict__ slide_m,
                  const int* __restrict__ hinge_m, const int* __restrict__ global_m,
                  const int* __restrict__ act_m, const int* __restrict__ morph_m,
                  const int* __restrict__ m_idx, const int* __restrict__ has_g,
                  const float* __restrict__ W_slide, const float* __restrict__ b_slide,
                  const float* __restrict__ W_hinge, const float* __restrict__ b_hinge,
                  const float* __restrict__ W_global, const float* __restrict__ b_global,
                  const float* __restrict__ W_act, const float* __restrict__ pos_emb,
                  const float* __restrict__ ln1_w, const float* __restrict__ ln1_b,
                  const float* __restrict__ qkv_b, const float* __restrict__ proj_b,
                  const float* __restrict__ ln2_w, const float* __restrict__ ln2_b,
                  const float* __restrict__ fc1_b, const float* __restrict__ fc2_b,
                  const float* __restrict__ ls1, const float* __restrict__ ls2,
                  const unsigned short* __restrict__ wsb, float* __restrict__ out)
{
    __shared__ __align__(16) unsigned char smem[152576];
    unsigned short* dbuf = (unsigned short*)smem;               // 2 halves x 2 tiles x 8KB = 32768B
    float* bias_lds = (float*)(smem + 32768);                   // 256 f32 (morph bias)
    const int tid = threadIdx.x;
    const int w = tid >> 6, lane = tid & 63, lq = lane & 15, lg = lane >> 4;
    unsigned short* slotA = (unsigned short*)(smem + 33792 + w * 14848);         // [16][264] bf16
    unsigned short* slotB = slotA + 4224;                                        // attn scratch
    unsigned short* q_s  = slotB;          // [16][40]
    unsigned short* k_s  = slotB + 640;    // [16][40]
    unsigned short* vT_s = slotB + 1280;   // [32][40]  (V^T: rows=dh, cols=key, keys 16..31 zero)
    unsigned short* p_s  = slotB + 2560;   // [16][40]  (rows=query, cols=key, keys 16..31 zero)

    const int G = blockIdx.x * 8 + w;
    const int b = G >> 7, t = G & 127;
    const int m = m_idx[b];

    if (tid < 256) bias_lds[tid] = morph_m[b * 256 + tid] ? 0.0f : -1e9f;
    for (int idx = lane; idx < 256; idx += 64) p_s[(idx >> 4) * 40 + 16 + (idx & 15)] = 0;
    for (int idx = lane; idx < 512; idx += 64) vT_s[(idx >> 4) * 40 + 16 + (idx & 15)] = 0;

    // ---- embedding into xr (fp32 regs) ----
    float xr[16][4];
    {
        const int hg = has_g[m];
        #pragma unroll
        for (int r = 0; r < 4; ++r) {
            const int j = lg * 4 + r;
            const size_t tok = (size_t)(b * 128 + t) * 16 + j;
            const float* ob = obs + tok * 16;
            float o0 = ob[0], o1 = ob[1], o2 = ob[2], o3 = ob[3], o4 = ob[4];
            int sl = slide_m[tok], hi = hinge_m[tok], gl = global_m[tok], am = act_m[tok];
            #pragma unroll
            for (int n = 0; n < 16; ++n) {
                int col = n * 16 + lq;
                float e = 0.f;
                if (sl) {
                    e = o0 * W_slide[col] + o1 * W_slide[256 + col] + b_slide[col];
                } else if (hi) {
                    e = o0 * W_hinge[col] + o1 * W_hinge[256 + col] + o2 * W_hinge[512 + col] + b_hinge[col];
                } else if (gl && hg) {
                    e = b_global[m * 256 + col]
                      + o0 * W_global[(m * 5 + 0) * 256 + col]
                      + o1 * W_global[(m * 5 + 1) * 256 + col]
                      + o2 * W_global[(m * 5 + 2) * 256 + col]
                      + o3 * W_global[(m * 5 + 3) * 256 + col]
                      + o4 * W_global[(m * 5 + 4) * 256 + col];
                }
                if (am) e += W_act[col];
                e += pos_emb[((size_t)m * 16 + j) * 256 + col];
                xr[n][r] = e;
            }
        }
    }
    __syncthreads();
    float bias4[4];
    #pragma unroll
    for (int r = 0; r < 4; ++r) bias4[r] = bias_lds[lq * 16 + lg * 4 + r];

    auto ldsAread = [&](int s) -> bf16x8 {
        return *(const bf16x8*)(slotA + lq * 264 + s * 32 + lg * 8);
    };
    auto bfrag = [&](int half, int tt, int s) -> bf16x8 {
        return *(const bf16x8*)(dbuf + half * 8192 + tt * 4096 + s * 512 + lane * 8);
    };
    auto stage2 = [&](int gtile, int half) {
        const unsigned short* src = wsb + (size_t)gtile * 4096 + tid * 8;
        unsigned short* dst = dbuf + half * 8192 + tid * 8;
        gload16(src, dst);
        gload16(src + 4096, dst + 4096);
    };
    auto layer_norm = [&](const float* lw, const float* lb) {
        float sm[4] = {0, 0, 0, 0}, sq[4] = {0, 0, 0, 0};
        #pragma unroll
        for (int n = 0; n < 16; ++n)
            #pragma unroll
            for (int r = 0; r < 4; ++r) { float v = xr[n][r]; sm[r] += v; sq[r] += v * v; }
        #pragma unroll
        for (int r = 0; r < 4; ++r) {
            #pragma unroll
            for (int mk = 1; mk <= 8; mk <<= 1) {
                sm[r] += __shfl_xor(sm[r], mk, 64);
                sq[r] += __shfl_xor(sq[r], mk, 64);
            }
        }
        float mean[4], rstd[4];
        #pragma unroll
        for (int r = 0; r < 4; ++r) {
            float mu = sm[r] * (1.f / 256.f);
            float var = sq[r] * (1.f / 256.f) - mu * mu;
            mean[r] = mu;
            rstd[r] = rsqrtf(var + 1e-5f);
        }
        #pragma unroll
        for (int n = 0; n < 16; ++n) {
            float wv = lw[n * 16 + lq], bv = lb[n * 16 + lq];
            #pragma unroll
            for (int r = 0; r < 4; ++r) {
                float xn = (xr[n][r] - mean[r]) * rstd[r] * wv + bv;
                slotA[(lg * 4 + r) * 264 + n * 16 + lq] = f2bf(xn);
            }
        }
    };

    const float SCALE = 0.17677669529663687f;  // 32^-0.5

    for (int layer = 0; layer < 4; ++layer) {
        const int TB = layer * 192;

        // ===== LN1 -> slotA, A-frags to regs =====
        layer_norm(ln1_w + layer * 256, ln1_b + layer * 256);
        bf16x8 av[8];
        #pragma unroll
        for (int s = 0; s < 8; ++s) av[s] = ldsAread(s);

        // ===== QKV (48 tiles, 24 rounds) + per-head attention =====
        stage2(TB, 0);
        __syncthreads();
        for (int r = 0; r < 24; ++r) {
            if (r + 1 < 24) stage2(TB + (r + 1) * 2, (r + 1) & 1);
            #pragma unroll
            for (int tt = 0; tt < 2; ++tt) {
                int tgt = r * 2 + tt;              // 0..47
                int h = tgt / 6, r6 = tgt % 6, sec = r6 >> 1, nn = r6 & 1;
                int col = sec * 256 + (2 * h + nn) * 16 + lq;
                float bv = qkv_b[layer * 768 + col];
                f32x4 acc = {bv, bv, bv, bv};
                #pragma unroll
                for (int s = 0; s < 8; ++s) acc = mfma16(av[s], bfrag(r & 1, tt, s), acc);
                if (sec == 0) {
                    #pragma unroll
                    for (int rr = 0; rr < 4; ++rr)
                        q_s[(lg * 4 + rr) * 40 + nn * 16 + lq] = f2bf(acc[rr]);
                } else if (sec == 1) {
                    #pragma unroll
                    for (int rr = 0; rr < 4; ++rr)
                        k_s[(lg * 4 + rr) * 40 + nn * 16 + lq] = f2bf(acc[rr]);
                } else {
                    #pragma unroll
                    for (int rr = 0; rr < 4; ++rr)
                        vT_s[(nn * 16 + lq) * 40 + lg * 4 + rr] = f2bf(acc[rr]);
                }
                if (r6 == 5) {
                    // attention for head h: S^T = K @ Q^T (16x16), softmax, PV
                    bf16x8 kf = *(const bf16x8*)(k_s + lq * 40 + lg * 8);
                    bf16x8 qf = *(const bf16x8*)(q_s + lq * 40 + lg * 8);
                    f32x4 z = {0, 0, 0, 0};
                    f32x4 st = mfma16(kf, qf, z);   // row=key=4lg+rr, col=query=lq
                    float p[4];
                    float mx = -3e38f;
                    #pragma unroll
                    for (int rr = 0; rr < 4; ++rr) {
                        p[rr] = st[rr] * SCALE + bias4[rr];
                        mx = fmaxf(mx, p[rr]);
                    }
                    mx = fmaxf(mx, __shfl_xor(mx, 16, 64));
                    mx = fmaxf(mx, __shfl_xor(mx, 32, 64));
                    float psum = 0.f;
                    #pragma unroll
                    for (int rr = 0; rr < 4; ++rr) { p[rr] = __expf(p[rr] - mx); psum += p[rr]; }
                    psum += __shfl_xor(psum, 16, 64);
                    psum += __shfl_xor(psum, 32, 64);
                    float inv = 1.f / psum;
                    #pragma unroll
                    for (int rr = 0; rr < 4; ++rr)
                        p_s[lq * 40 + lg * 4 + rr] = f2bf(p[rr] * inv);
                    bf16x8 pf = *(const bf16x8*)(p_s + lq * 40 + lg * 8);
                    #pragma unroll
                    for (int dt = 0; dt < 2; ++dt) {
                        bf16x8 vf = *(const bf16x8*)(vT_s + (dt * 16 + lq) * 40 + lg * 8);
                        f32x4 o = mfma16(pf, vf, z);
                        #pragma unroll
                        for (int rr = 0; rr < 4; ++rr)
                            slotA[(lg * 4 + rr) * 264 + (2 * h + dt) * 16 + lq] = f2bf(o[rr]);
                    }
                }
            }
            __syncthreads();
        }

        // ===== proj (16 tiles, 8 rounds), residual with ls1 =====
        bf16x8 ao[8];
        #pragma unroll
        for (int s = 0; s < 8; ++s) ao[s] = ldsAread(s);
        stage2(TB + 48, 0);
        __syncthreads();
        #pragma unroll
        for (int r = 0; r < 8; ++r) {
            if (r + 1 < 8) stage2(TB + 48 + (r + 1) * 2, (r + 1) & 1);
            #pragma unroll
            for (int tt = 0; tt < 2; ++tt) {
                int nt = r * 2 + tt;
                int col = nt * 16 + lq;
                float bv = proj_b[layer * 256 + col];
                f32x4 acc = {bv, bv, bv, bv};
                #pragma unroll
                for (int s = 0; s < 8; ++s) acc = mfma16(ao[s], bfrag(r & 1, tt, s), acc);
                float l1 = ls1[layer * 256 + col];
                #pragma unroll
                for (int rr = 0; rr < 4; ++rr) xr[nt][rr] += l1 * acc[rr];
            }
            __syncthreads();
        }

        // ===== LN2 -> slotA, A-frags =====
        layer_norm(ln2_w + layer * 256, ln2_b + layer * 256);
        bf16x8 an[8];
        #pragma unroll
        for (int s = 0; s < 8; ++s) an[s] = ldsAread(s);

        // ===== MLP: 4 chunks of (fc1 16 tiles -> gelu -> fc2 16 tiles) =====
        f32x4 fa[16];
        for (int c = 0; c < 4; ++c) {
            stage2(TB + 64 + c * 16, 0);
            __syncthreads();
            #pragma unroll
            for (int r = 0; r < 8; ++r) {
                if (r + 1 < 8) stage2(TB + 64 + c * 16 + (r + 1) * 2, (r + 1) & 1);
                #pragma unroll
                for (int tt = 0; tt < 2; ++tt) {
                    int ntl = r * 2 + tt;
                    int col = c * 256 + ntl * 16 + lq;
                    float bv = fc1_b[layer * 1024 + col];
                    f32x4 acc = {bv, bv, bv, bv};
                    #pragma unroll
                    for (int s = 0; s < 8; ++s) acc = mfma16(an[s], bfrag(r & 1, tt, s), acc);
                    #pragma unroll
                    for (int rr = 0; rr < 4; ++rr) {
                        float hv = acc[rr];
                        float y = 0.7978845608028654f * (hv + 0.044715f * hv * hv * hv);
                        float th = 1.0f - 2.0f / (__expf(2.0f * y) + 1.0f);
                        float g = 0.5f * hv * (1.0f + th);
                        slotA[(lg * 4 + rr) * 264 + ntl * 16 + lq] = f2bf(g);
                    }
                }
                __syncthreads();
            }
            bf16x8 ah[8];
            #pragma unroll
            for (int s = 0; s < 8; ++s) ah[s] = ldsAread(s);
            stage2(TB + 128 + c * 16, 0);
            __syncthreads();
            #pragma unroll
            for (int r = 0; r < 8; ++r) {
                if (r + 1 < 8) stage2(TB + 128 + c * 16 + (r + 1) * 2, (r + 1) & 1);
                #pragma unroll
                for (int tt = 0; tt < 2; ++tt) {
                    int nt = r * 2 + tt;
                    f32x4 acc;
                    if (c == 0) {
                        float bv = fc2_b[layer * 256 + nt * 16 + lq];
                        acc = {bv, bv, bv, bv};
                    } else {
                        acc = fa[nt];
                    }
                    #pragma unroll
                    for (int s = 0; s < 8; ++s) acc = mfma16(ah[s], bfrag(r & 1, tt, s), acc);
                    fa[nt] = acc;
                }
                __syncthreads();
            }
        }
        #pragma unroll
        for (int nt = 0; nt < 16; ++nt) {
            float l2 = ls2[layer * 256 + nt * 16 + lq];
            #pragma unroll
            for (int rr = 0; rr < 4; ++rr) xr[nt][rr] += l2 * fa[nt][rr];
        }
    }

    // ---- store ----
    float* op = out + (size_t)G * 4096;
    #pragma unroll
    for (int n = 0; n < 16; ++n)
        #pragma unroll
        for (int rr = 0; rr < 4; ++rr)
            op[(lg * 4 + rr) * 256 + n * 16 + lq] = xr[n][rr];
}

extern "C" void kernel_launch(void* const* d_in, const int* in_sizes, int n_in,
                              void* d_out, int out_size, void* d_ws, size_t ws_size,
                              hipStream_t stream) {
    (void)in_sizes; (void)n_in; (void)out_size; (void)ws_size;
    const float* obs      = (const float*)d_in[0];
    const int*   slide_m  = (const int*)d_in[1];
    const int*   hinge_m  = (const int*)d_in[2];
    const int*   global_m = (const int*)d_in[3];
    const int*   act_m    = (const int*)d_in[4];
    const int*   morph_m  = (const int*)d_in[5];
    const int*   m_idx    = (const int*)d_in[6];
    const int*   has_g    = (const int*)d_in[7];
    const float* W_slide  = (const float*)d_in[8];
    const float* b_slide  = (const float*)d_in[9];
    const float* W_hinge  = (const float*)d_in[10];
    const float* b_hinge  = (const float*)d_in[11];
    const float* W_global = (const float*)d_in[12];
    const float* b_global = (const float*)d_in[13];
    const float* W_act    = (const float*)d_in[14];
    const float* pos_emb  = (const float*)d_in[15];
    const float* ln1_w    = (const float*)d_in[16];
    const float* ln1_b    = (const float*)d_in[17];
    const float* qkv_w    = (const float*)d_in[18];
    const float* qkv_b    = (const float*)d_in[19];
    const float* proj_w   = (const float*)d_in[20];
    const float* proj_b   = (const float*)d_in[21];
    const float* ln2_w    = (const float*)d_in[22];
    const float* ln2_b    = (const float*)d_in[23];
    const float* fc1_w    = (const float*)d_in[24];
    const float* fc1_b    = (const float*)d_in[25];
    const float* fc2_w    = (const float*)d_in[26];
    const float* fc2_b    = (const float*)d_in[27];
    const float* ls1      = (const float*)d_in[28];
    const float* ls2      = (const float*)d_in[29];
    unsigned short* wsb = (unsigned short*)d_ws;

    prep_kernel<<<768, 256, 0, stream>>>(qkv_w, proj_w, fc1_w, fc2_w, wsb);
    fused_kernel<<<512, 512, 0, stream>>>(obs, slide_m, hinge_m, global_m, act_m, morph_m,
        m_idx, has_g, W_slide, b_slide, W_hinge, b_hinge, W_global, b_global, W_act, pos_emb,
        ln1_w, ln1_b, qkv_b, proj_b, ln2_w, ln2_b, fc1_b, fc2_b, ls1, ls2, wsb, (float*)d_out);
}